// Round 1
// 697.901 us; speedup vs baseline: 1.0774x; 1.0774x over previous
//
#include <hip/hip_runtime.h>
#include <stdint.h>

#define D_ 128
#define NB_ 20
#define SCAN_B 1024

typedef __bf16 bf16x8 __attribute__((ext_vector_type(8)));
typedef float f32x4 __attribute__((ext_vector_type(4)));
typedef float f32x2 __attribute__((ext_vector_type(2)));

// fast silu: x * rcp(1+exp(-x)); v_rcp_f32 rel-err ~2^-22, fine at bf16 tolerance
__device__ __forceinline__ float silu_f(float x) {
  return x * __builtin_amdgcn_rcpf(1.0f + __expf(-x));
}
__device__ __forceinline__ f32x2 silu2(f32x2 x) {
  return (f32x2){silu_f(x.x), silu_f(x.y)};
}
__device__ __forceinline__ f32x2 fsplat(float x) { return (f32x2){x, x}; }

__device__ __forceinline__ float bf2f(unsigned short u) {
  return __uint_as_float(((unsigned int)u) << 16);
}
__device__ __forceinline__ unsigned short f2bf(float f) {
  unsigned int x = __float_as_uint(f);
  return (unsigned short)((x + 0x7fffu + ((x >> 16) & 1u)) >> 16);
}

// ---------------------------------------------------------------------------
// prep ranges:
//  [0, 2688):           Mfold = A2@W1c (20x128), b1p = b1 + ab2@W1c
//  [2688, 19072):       W2uT bf16: W2uT[n*128+k] = (W2@Wu)[k][n]
//  [19072, 19200):      c2 = b2 @ Wu
//  [19200, 51968):      W1T bf16: W1T[half*128+n][k] = W1[half*128+k][n]
__global__ __launch_bounds__(256) void prep_kernel(
    const float* __restrict__ A2, const float* __restrict__ ab2,
    const float* __restrict__ W1, const float* __restrict__ b1,
    const float* __restrict__ W2, const float* __restrict__ Wu,
    const float* __restrict__ b2,
    float* __restrict__ Mfold, float* __restrict__ b1p,
    unsigned short* __restrict__ W2uT, float* __restrict__ c2,
    unsigned short* __restrict__ W1T) {
  int tid = blockIdx.x * blockDim.x + threadIdx.x;
  if (tid < 21 * D_) {
    int r = tid >> 7, c = tid & (D_ - 1);
    if (r < NB_) {
      float acc = 0.f;
      for (int j = 0; j < NB_; ++j) acc += A2[r * NB_ + j] * W1[(2 * D_ + j) * D_ + c];
      Mfold[r * D_ + c] = acc;
    } else {
      float acc = b1[c];
      for (int j = 0; j < NB_; ++j) acc += ab2[j] * W1[(2 * D_ + j) * D_ + c];
      b1p[c] = acc;
    }
  } else if (tid < 2688 + 16384) {
    int i = tid - 2688;
    int n = i >> 7, k = i & 127;
    float acc = 0.f;
    for (int m = 0; m < D_; ++m) acc += W2[k * D_ + m] * Wu[m * D_ + n];
    W2uT[i] = f2bf(acc);
  } else if (tid < 19072 + 128) {
    int n = tid - 19072;
    float acc = 0.f;
    for (int m = 0; m < D_; ++m) acc += b2[m] * Wu[m * D_ + n];
    c2[n] = acc;
  } else if (tid < 19200 + 32768) {
    int i = tid - 19200;
    int r = i >> 7, k = i & 127;
    int half = r >> 7, n = r & 127;
    W1T[i] = f2bf(W1[(size_t)(half * 128 + k) * D_ + n]);
  }
}

// ---------------------------------------------------------------------------
// MFMA pq: P = edge_attr @ W1[0:128], Q = edge_attr @ W1[128:256], bf16 out.
__global__ __launch_bounds__(256) void pq_mfma(const float* __restrict__ edge_attr,
                                               const unsigned short* __restrict__ W1T,
                                               unsigned short* __restrict__ P,
                                               unsigned short* __restrict__ Q, int E) {
  const int lane = threadIdx.x & 63;
  const int wave = threadIdx.x >> 6;
  const int e0 = (blockIdx.x * 4 + wave) * 16;
  if (e0 >= E) return;
  const int row = lane & 15;
  const int quad = lane >> 4;
  int e = e0 + row; if (e >= E) e = E - 1;

  union { bf16x8 v; unsigned short u[8]; } afr[4];
  const float* arow = edge_attr + (size_t)e * D_ + quad * 8;
#pragma unroll
  for (int kt = 0; kt < 4; ++kt) {
    float4 f0 = *(const float4*)(arow + kt * 32);
    float4 f1 = *(const float4*)(arow + kt * 32 + 4);
    afr[kt].u[0] = f2bf(f0.x); afr[kt].u[1] = f2bf(f0.y);
    afr[kt].u[2] = f2bf(f0.z); afr[kt].u[3] = f2bf(f0.w);
    afr[kt].u[4] = f2bf(f1.x); afr[kt].u[5] = f2bf(f1.y);
    afr[kt].u[6] = f2bf(f1.z); afr[kt].u[7] = f2bf(f1.w);
  }
#pragma unroll
  for (int half = 0; half < 2; ++half) {
    unsigned short* Obase = half ? Q : P;
#pragma unroll
    for (int nt = 0; nt < 8; ++nt) {
      const unsigned short* wrow =
          W1T + ((size_t)(half * 128 + nt * 16 + row)) * 128 + quad * 8;
      f32x4 acc = {0.f, 0.f, 0.f, 0.f};
#pragma unroll
      for (int kt = 0; kt < 4; ++kt) {
        bf16x8 bfr = *(const bf16x8*)(wrow + kt * 32);
        acc = __builtin_amdgcn_mfma_f32_16x16x32_bf16(afr[kt].v, bfr, acc, 0, 0, 0);
      }
      int n = nt * 16 + row;
#pragma unroll
      for (int i = 0; i < 4; ++i) {
        int er = e0 + quad * 4 + i;
        if (er < E) Obase[(size_t)er * D_ + n] = f2bf(acc[i]);
      }
    }
  }
}

// ---------------------------------------------------------------------------
// Counting sort by e_ij
__global__ void hist_kernel(const int* __restrict__ tbe, int* __restrict__ cnt, int T_) {
  int t = blockIdx.x * blockDim.x + threadIdx.x;
  if (t < T_) atomicAdd(&cnt[((const int2*)tbe)[t].x], 1);
}

__global__ __launch_bounds__(SCAN_B) void scan1_kernel(const int* __restrict__ cnt,
                                                       int* __restrict__ pre,
                                                       int* __restrict__ bsum, int E) {
  __shared__ int lds[SCAN_B];
  int tid = threadIdx.x, i = blockIdx.x * SCAN_B + tid;
  int v = (i < E) ? cnt[i] : 0;
  lds[tid] = v;
  __syncthreads();
  for (int d = 1; d < SCAN_B; d <<= 1) {
    int add = (tid >= d) ? lds[tid - d] : 0;
    __syncthreads();
    lds[tid] += add;
    __syncthreads();
  }
  if (i < E) pre[i] = lds[tid] - v;
  if (tid == SCAN_B - 1) bsum[blockIdx.x] = lds[tid];
}

__global__ void scan2_kernel(int* __restrict__ bsum, int nb) {
  __shared__ int lds[256];
  int tid = threadIdx.x;
  int v = (tid < nb) ? bsum[tid] : 0;
  lds[tid] = v;
  __syncthreads();
  for (int d = 1; d < 256; d <<= 1) {
    int add = (tid >= d) ? lds[tid - d] : 0;
    __syncthreads();
    lds[tid] += add;
    __syncthreads();
  }
  if (tid < nb) bsum[tid] = lds[tid] - v;
}

__global__ __launch_bounds__(SCAN_B) void scan3_kernel(const int* __restrict__ pre,
                                                       const int* __restrict__ bsum,
                                                       int* __restrict__ offs,
                                                       int* __restrict__ cursor, int E, int T_) {
  int i = blockIdx.x * SCAN_B + threadIdx.x;
  if (i < E) {
    int o = pre[i] + bsum[blockIdx.x];
    offs[i] = o;
    cursor[i] = o;
  }
  if (i == 0) offs[E] = T_;
}

// Scatter + fused geometry: writes seik[pos] and g[pos][20] (fp32, float4 x5).
__global__ void scatter_kernel(const int* __restrict__ tbe, int* __restrict__ cursor,
                               const float* __restrict__ edge_vectors,
                               const float* __restrict__ A1, const float* __restrict__ ab1,
                               int* __restrict__ seik, float* __restrict__ gT, int T_) {
  int t = blockIdx.x * blockDim.x + threadIdx.x;
  if (t >= T_) return;
  int2 v = ((const int2*)tbe)[t];
  int pos = atomicAdd(&cursor[v.x], 1);
  seik[pos] = v.y;
  const float* vj = edge_vectors + 3 * (size_t)v.x;
  const float* vk = edge_vectors + 3 * (size_t)v.y;
  float jx = vj[0], jy = vj[1], jz = vj[2];
  float kx = vk[0], ky = vk[1], kz = vk[2];
  float lij = fmaxf(__builtin_amdgcn_sqrtf(jx * jx + jy * jy + jz * jz), 1e-6f);
  float lik = fmaxf(__builtin_amdgcn_sqrtf(kx * kx + ky * ky + kz * kz), 1e-6f);
  float cosv = (jx * kx + jy * ky + jz * kz) * __builtin_amdgcn_rcpf(lij * lik);
  cosv = fminf(fmaxf(cosv, -1.f), 1.f);
  union { float4 v4[5]; float f[NB_]; } gr;
#pragma unroll
  for (int k = 0; k < NB_; ++k)
    gr.f[k] = silu_f(lij * A1[k] + lik * A1[NB_ + k] + cosv * A1[2 * NB_ + k] + ab1[k]);
  float4* gp = (float4*)(gT + (size_t)pos * NB_);
#pragma unroll
  for (int i = 0; i < 5; ++i) gp[i] = gr.v4[i];
}

// ---------------------------------------------------------------------------
// One wave per edge segment, software-pipelined 2-deep:
//   s[e] = sum_t silu(P[e] + Q[eik_t] + g_t@M + b1p)
// seik is padded by 8 zeroed ints past T; gT padded by 8 rows (values unread).
struct G5 { float4 a, b, c, d, e; };

__device__ __forceinline__ G5 loadG(const char* __restrict__ gc, int t) {
  const float4* p = (const float4*)(
      gc + 80u * (unsigned)__builtin_amdgcn_readfirstlane(t));
  G5 g;
  g.a = p[0]; g.b = p[1]; g.c = p[2]; g.d = p[3]; g.e = p[4];
  return g;
}

__device__ __forceinline__ void body_acc(f32x2& acc, const f32x2 base,
                                         const G5& G, ushort2 qq,
                                         const f32x2* __restrict__ m) {
  const float* Gf = (const float*)&G;
  f32x2 u = base + (f32x2){bf2f(qq.x), bf2f(qq.y)};
  f32x2 ub = fsplat(0.f);
#pragma unroll
  for (int k = 0; k < NB_; k += 2) {
    u  += fsplat(Gf[k])     * m[k];
    ub += fsplat(Gf[k + 1]) * m[k + 1];
  }
  u += ub;
  acc += silu2(u);
}

__global__ __launch_bounds__(256, 4) void seg_kernel(
    const int* __restrict__ offs, const int* __restrict__ seik,
    const float* __restrict__ gT,
    const float* __restrict__ Mfold, const float* __restrict__ b1p,
    const unsigned short* __restrict__ P, const unsigned short* __restrict__ Q,
    float* __restrict__ s_out, int E) {
  const int lane = threadIdx.x & 63;
  const int wid = (blockIdx.x * blockDim.x + threadIdx.x) >> 6;
  const int nw = (gridDim.x * blockDim.x) >> 6;

  f32x2 m[NB_];
#pragma unroll
  for (int k = 0; k < NB_; ++k) {
    float2 t2 = *(const float2*)(Mfold + k * D_ + 2 * lane);
    m[k] = (f32x2){t2.x, t2.y};
  }
  const float2 bbt = *(const float2*)(b1p + 2 * lane);
  const f32x2 bb = (f32x2){bbt.x, bbt.y};

  const char* Qc = (const char*)Q;
  const char* Pc = (const char*)P;
  const char* gc = (const char*)gT;
  const unsigned loff = (unsigned)lane * 4u;

  int e = wid;
  if (e >= E) return;
  int o0 = offs[e], o1 = offs[e + 1];
  int eik0 = seik[__builtin_amdgcn_readfirstlane(o0)];
  ushort2 pp = *(const ushort2*)(Pc + ((unsigned)e << 8) + loff);

  for (; e < E; e += nw) {
    const int en = e + nw;
    int o0n = 0, o1n = 0, eik0n = 0;
    ushort2 ppn = make_ushort2(0, 0);
    if (en < E) {
      o0n = offs[en]; o1n = offs[en + 1];
      ppn = *(const ushort2*)(Pc + ((unsigned)en << 8) + loff);
      eik0n = seik[__builtin_amdgcn_readfirstlane(o0n)];
    }
    f32x2 acc = (f32x2){0.f, 0.f};
    if (o1 > o0) {
      const f32x2 base = (f32x2){bf2f(pp.x), bf2f(pp.y)} + bb;
      int t = o0;
      // index pipeline: eik for t..t+3 resident (seik padded to T+8, pad=0)
      int eik_a = eik0;
      int eik_b = seik[__builtin_amdgcn_readfirstlane(o0 + 1)];
      int eik_c = seik[__builtin_amdgcn_readfirstlane(o0 + 2)];
      int eik_d = seik[__builtin_amdgcn_readfirstlane(o0 + 3)];
      ushort2 qq_a = *(const ushort2*)(Qc + ((unsigned)eik_a << 8) + loff);
      ushort2 qq_b = *(const ushort2*)(Qc + ((unsigned)eik_b << 8) + loff);
      G5 Ga = loadG(gc, t);
      G5 Gb;
      for (; t + 1 < o1; t += 2) {
        // issue next Q rows + next G + next seik before the compute bodies
        ushort2 qq_c = *(const ushort2*)(Qc + ((unsigned)eik_c << 8) + loff);
        Gb = loadG(gc, t + 1);
        int eik_e = seik[__builtin_amdgcn_readfirstlane(t + 4)];
        int eik_f = seik[__builtin_amdgcn_readfirstlane(t + 5)];
        body_acc(acc, base, Ga, qq_a, m);
        ushort2 qq_d = *(const ushort2*)(Qc + ((unsigned)eik_d << 8) + loff);
        Ga = loadG(gc, t + 2);
        body_acc(acc, base, Gb, qq_b, m);
        qq_a = qq_c; qq_b = qq_d;
        eik_c = eik_e; eik_d = eik_f;
      }
      if (t < o1) body_acc(acc, base, Ga, qq_a, m);
    }
    *(f32x2*)(s_out + (size_t)e * D_ + 2 * lane) = acc;
    o0 = o0n; o1 = o1n; pp = ppn; eik0 = eik0n;
  }
}

// ---------------------------------------------------------------------------
// In-place MFMA: out[e] = s[e] @ W2u + cnt[e]*c2 + bu
__global__ __launch_bounds__(256) void out_mfma(float* __restrict__ io,
                                                const unsigned short* __restrict__ W2uT,
                                                const float* __restrict__ c2,
                                                const float* __restrict__ bu,
                                                const int* __restrict__ cnt, int E) {
  const int lane = threadIdx.x & 63;
  const int wave = threadIdx.x >> 6;
  const int e0 = (blockIdx.x * 4 + wave) * 16;
  if (e0 >= E) return;
  const int row = lane & 15;
  const int quad = lane >> 4;
  int e = e0 + row; if (e >= E) e = E - 1;

  union { bf16x8 v; unsigned short u[8]; } afr[4];
  const float* arow = io + (size_t)e * D_ + quad * 8;
#pragma unroll
  for (int kt = 0; kt < 4; ++kt) {
    float4 f0 = *(const float4*)(arow + kt * 32);
    float4 f1 = *(const float4*)(arow + kt * 32 + 4);
    afr[kt].u[0] = f2bf(f0.x); afr[kt].u[1] = f2bf(f0.y);
    afr[kt].u[2] = f2bf(f0.z); afr[kt].u[3] = f2bf(f0.w);
    afr[kt].u[4] = f2bf(f1.x); afr[kt].u[5] = f2bf(f1.y);
    afr[kt].u[6] = f2bf(f1.z); afr[kt].u[7] = f2bf(f1.w);
  }
  float nf[4];
#pragma unroll
  for (int i = 0; i < 4; ++i) {
    int er = e0 + quad * 4 + i;
    nf[i] = (float)cnt[(er < E) ? er : (E - 1)];
  }
#pragma unroll
  for (int nt = 0; nt < 8; ++nt) {
    const unsigned short* wrow = W2uT + ((size_t)(nt * 16 + row)) * 128 + quad * 8;
    f32x4 acc = {0.f, 0.f, 0.f, 0.f};
#pragma unroll
    for (int kt = 0; kt < 4; ++kt) {
      bf16x8 bfr = *(const bf16x8*)(wrow + kt * 32);
      acc = __builtin_amdgcn_mfma_f32_16x16x32_bf16(afr[kt].v, bfr, acc, 0, 0, 0);
    }
    int n = nt * 16 + row;
    float c2n = c2[n], bun = bu[n];
#pragma unroll
    for (int i = 0; i < 4; ++i) {
      int er = e0 + quad * 4 + i;
      if (er < E) io[(size_t)er * D_ + n] = acc[i] + nf[i] * c2n + bun;
    }
  }
}

// ---------------------------------------------------------------------------
extern "C" void kernel_launch(void* const* d_in, const int* in_sizes, int n_in,
                              void* d_out, int out_size, void* d_ws, size_t ws_size,
                              hipStream_t stream) {
  const float* edge_attr    = (const float*)d_in[0];
  const int*   tbe          = (const int*)d_in[2];
  const float* edge_vectors = (const float*)d_in[3];
  const float* A1  = (const float*)d_in[4];
  const float* ab1 = (const float*)d_in[5];
  const float* A2  = (const float*)d_in[6];
  const float* ab2 = (const float*)d_in[7];
  const float* W1  = (const float*)d_in[8];
  const float* b1  = (const float*)d_in[9];
  const float* W2  = (const float*)d_in[10];
  const float* b2  = (const float*)d_in[11];
  const float* Wu  = (const float*)d_in[12];
  const float* bu  = (const float*)d_in[13];
  const int E = in_sizes[0] / D_;
  const int T = in_sizes[2] / 2;
  float* out = (float*)d_out;

  char* w = (char*)d_ws;
  auto carve = [&](size_t bytes) -> char* {
    char* p = w;
    w += (bytes + 255) & ~(size_t)255;
    return p;
  };
  unsigned short* P = (unsigned short*)carve((size_t)E * D_ * 2);
  unsigned short* Q = (unsigned short*)carve((size_t)E * D_ * 2);
  float* gT   = (float*)carve(((size_t)T + 8) * NB_ * 4);   // +8 pad rows (unread values)
  int* seik   = (int*)carve(((size_t)T + 8) * 4);           // +8 pad ints (zeroed)
  int* cnt    = (int*)carve((size_t)E * 4);
  int* pre    = (int*)carve((size_t)E * 4);
  int* offs   = (int*)carve((size_t)(E + 1) * 4);
  int* cursor = (int*)carve((size_t)E * 4);
  int* bsum   = (int*)carve(1024 * 4);
  float* Mfold = (float*)carve(NB_ * D_ * 4);
  float* b1p   = (float*)carve(D_ * 4);
  unsigned short* W2uT = (unsigned short*)carve(D_ * D_ * 2);
  float* c2    = (float*)carve(D_ * 4);
  unsigned short* W1T = (unsigned short*)carve(256 * 128 * 2);

  const int nb_scan = (E + SCAN_B - 1) / SCAN_B;

  hipMemsetAsync(cnt, 0, (size_t)E * 4, stream);
  hipMemsetAsync(seik + T, 0, 8 * 4, stream);  // zero the index pad

  prep_kernel<<<(51968 + 255) / 256, 256, 0, stream>>>(A2, ab2, W1, b1, W2, Wu, b2,
                                                       Mfold, b1p, W2uT, c2, W1T);
  pq_mfma<<<(E + 63) / 64, 256, 0, stream>>>(edge_attr, W1T, P, Q, E);

  hist_kernel<<<(T + 255) / 256, 256, 0, stream>>>(tbe, cnt, T);
  scan1_kernel<<<nb_scan, SCAN_B, 0, stream>>>(cnt, pre, bsum, E);
  scan2_kernel<<<1, 256, 0, stream>>>(bsum, nb_scan);
  scan3_kernel<<<nb_scan, SCAN_B, 0, stream>>>(pre, bsum, offs, cursor, E, T);
  scatter_kernel<<<(T + 255) / 256, 256, 0, stream>>>(tbe, cursor, edge_vectors,
                                                      A1, ab1, seik, gT, T);

  seg_kernel<<<1024, 256, 0, stream>>>(offs, seik, gT, Mfold, b1p, P, Q, out, E);
  out_mfma<<<(E + 63) / 64, 256, 0, stream>>>(out, W2uT, c2, bu, cnt, E);
}

// Round 2
// 695.048 us; speedup vs baseline: 1.0818x; 1.0041x over previous
//
#include <hip/hip_runtime.h>
#include <stdint.h>

#define D_ 128
#define NB_ 20
#define SCAN_B 1024
#define SEG_BLOCKS 2048
#define NWAVES (SEG_BLOCKS * 256 / 64)

typedef __bf16 bf16x8 __attribute__((ext_vector_type(8)));
typedef float f32x4 __attribute__((ext_vector_type(4)));
typedef float f32x2 __attribute__((ext_vector_type(2)));

// fast silu: x * rcp(1+exp(-x)); v_rcp_f32 rel-err ~2^-22, fine at bf16 tolerance
__device__ __forceinline__ float silu_f(float x) {
  return x * __builtin_amdgcn_rcpf(1.0f + __expf(-x));
}
__device__ __forceinline__ f32x2 silu2(f32x2 x) {
  return (f32x2){silu_f(x.x), silu_f(x.y)};
}
__device__ __forceinline__ f32x2 fsplat(float x) { return (f32x2){x, x}; }

__device__ __forceinline__ float bf2f(unsigned short u) {
  return __uint_as_float(((unsigned int)u) << 16);
}
__device__ __forceinline__ unsigned short f2bf(float f) {
  unsigned int x = __float_as_uint(f);
  return (unsigned short)((x + 0x7fffu + ((x >> 16) & 1u)) >> 16);
}

// ---------------------------------------------------------------------------
// prep ranges:
//  [0, 2688):           Mfold = A2@W1c (20x128), b1p = b1 + ab2@W1c
//  [2688, 19072):       W2uT bf16: W2uT[n*128+k] = (W2@Wu)[k][n]
//  [19072, 19200):      c2 = b2 @ Wu
//  [19200, 51968):      W1T bf16: W1T[half*128+n][k] = W1[half*128+k][n]
__global__ __launch_bounds__(256) void prep_kernel(
    const float* __restrict__ A2, const float* __restrict__ ab2,
    const float* __restrict__ W1, const float* __restrict__ b1,
    const float* __restrict__ W2, const float* __restrict__ Wu,
    const float* __restrict__ b2,
    float* __restrict__ Mfold, float* __restrict__ b1p,
    unsigned short* __restrict__ W2uT, float* __restrict__ c2,
    unsigned short* __restrict__ W1T) {
  int tid = blockIdx.x * blockDim.x + threadIdx.x;
  if (tid < 21 * D_) {
    int r = tid >> 7, c = tid & (D_ - 1);
    if (r < NB_) {
      float acc = 0.f;
      for (int j = 0; j < NB_; ++j) acc += A2[r * NB_ + j] * W1[(2 * D_ + j) * D_ + c];
      Mfold[r * D_ + c] = acc;
    } else {
      float acc = b1[c];
      for (int j = 0; j < NB_; ++j) acc += ab2[j] * W1[(2 * D_ + j) * D_ + c];
      b1p[c] = acc;
    }
  } else if (tid < 2688 + 16384) {
    int i = tid - 2688;
    int n = i >> 7, k = i & 127;
    float acc = 0.f;
    for (int m = 0; m < D_; ++m) acc += W2[k * D_ + m] * Wu[m * D_ + n];
    W2uT[i] = f2bf(acc);
  } else if (tid < 19072 + 128) {
    int n = tid - 19072;
    float acc = 0.f;
    for (int m = 0; m < D_; ++m) acc += b2[m] * Wu[m * D_ + n];
    c2[n] = acc;
  } else if (tid < 19200 + 32768) {
    int i = tid - 19200;
    int r = i >> 7, k = i & 127;
    int half = r >> 7, n = r & 127;
    W1T[i] = f2bf(W1[(size_t)(half * 128 + k) * D_ + n]);
  }
}

// ---------------------------------------------------------------------------
// MFMA pq: P = edge_attr @ W1[0:128], Q = edge_attr @ W1[128:256], bf16 out.
__global__ __launch_bounds__(256) void pq_mfma(const float* __restrict__ edge_attr,
                                               const unsigned short* __restrict__ W1T,
                                               unsigned short* __restrict__ P,
                                               unsigned short* __restrict__ Q, int E) {
  const int lane = threadIdx.x & 63;
  const int wave = threadIdx.x >> 6;
  const int e0 = (blockIdx.x * 4 + wave) * 16;
  if (e0 >= E) return;
  const int row = lane & 15;
  const int quad = lane >> 4;
  int e = e0 + row; if (e >= E) e = E - 1;

  union { bf16x8 v; unsigned short u[8]; } afr[4];
  const float* arow = edge_attr + (size_t)e * D_ + quad * 8;
#pragma unroll
  for (int kt = 0; kt < 4; ++kt) {
    float4 f0 = *(const float4*)(arow + kt * 32);
    float4 f1 = *(const float4*)(arow + kt * 32 + 4);
    afr[kt].u[0] = f2bf(f0.x); afr[kt].u[1] = f2bf(f0.y);
    afr[kt].u[2] = f2bf(f0.z); afr[kt].u[3] = f2bf(f0.w);
    afr[kt].u[4] = f2bf(f1.x); afr[kt].u[5] = f2bf(f1.y);
    afr[kt].u[6] = f2bf(f1.z); afr[kt].u[7] = f2bf(f1.w);
  }
#pragma unroll
  for (int half = 0; half < 2; ++half) {
    unsigned short* Obase = half ? Q : P;
#pragma unroll
    for (int nt = 0; nt < 8; ++nt) {
      const unsigned short* wrow =
          W1T + ((size_t)(half * 128 + nt * 16 + row)) * 128 + quad * 8;
      f32x4 acc = {0.f, 0.f, 0.f, 0.f};
#pragma unroll
      for (int kt = 0; kt < 4; ++kt) {
        bf16x8 bfr = *(const bf16x8*)(wrow + kt * 32);
        acc = __builtin_amdgcn_mfma_f32_16x16x32_bf16(afr[kt].v, bfr, acc, 0, 0, 0);
      }
      int n = nt * 16 + row;
#pragma unroll
      for (int i = 0; i < 4; ++i) {
        int er = e0 + quad * 4 + i;
        if (er < E) Obase[(size_t)er * D_ + n] = f2bf(acc[i]);
      }
    }
  }
}

// ---------------------------------------------------------------------------
// Counting sort by e_ij
__global__ void hist_kernel(const int* __restrict__ tbe, int* __restrict__ cnt, int T_) {
  int t = blockIdx.x * blockDim.x + threadIdx.x;
  if (t < T_) atomicAdd(&cnt[((const int2*)tbe)[t].x], 1);
}

__global__ __launch_bounds__(SCAN_B) void scan1_kernel(const int* __restrict__ cnt,
                                                       int* __restrict__ pre,
                                                       int* __restrict__ bsum, int E) {
  __shared__ int lds[SCAN_B];
  int tid = threadIdx.x, i = blockIdx.x * SCAN_B + tid;
  int v = (i < E) ? cnt[i] : 0;
  lds[tid] = v;
  __syncthreads();
  for (int d = 1; d < SCAN_B; d <<= 1) {
    int add = (tid >= d) ? lds[tid - d] : 0;
    __syncthreads();
    lds[tid] += add;
    __syncthreads();
  }
  if (i < E) pre[i] = lds[tid] - v;
  if (tid == SCAN_B - 1) bsum[blockIdx.x] = lds[tid];
}

__global__ void scan2_kernel(int* __restrict__ bsum, int nb) {
  __shared__ int lds[256];
  int tid = threadIdx.x;
  int v = (tid < nb) ? bsum[tid] : 0;
  lds[tid] = v;
  __syncthreads();
  for (int d = 1; d < 256; d <<= 1) {
    int add = (tid >= d) ? lds[tid - d] : 0;
    __syncthreads();
    lds[tid] += add;
    __syncthreads();
  }
  if (tid < nb) bsum[tid] = lds[tid] - v;
}

__global__ __launch_bounds__(SCAN_B) void scan3_kernel(const int* __restrict__ pre,
                                                       const int* __restrict__ bsum,
                                                       int* __restrict__ offs,
                                                       int* __restrict__ cursor, int E, int T_) {
  int i = blockIdx.x * SCAN_B + threadIdx.x;
  if (i < E) {
    int o = pre[i] + bsum[blockIdx.x];
    offs[i] = o;
    cursor[i] = o;
  }
  if (i == 0) offs[E] = T_;
}

// Per-wave balanced segment ranges: wstart[w] = e such that triplet target
// w*T/NW lands in segment e. Each segment e writes the (possibly empty) range
// of waves whose targets fall inside [offs[e], offs[e+1]).
__global__ __launch_bounds__(256) void wfill_kernel(const int* __restrict__ offs,
                                                    int* __restrict__ wstart,
                                                    int E, int T_, int NW) {
  int e = blockIdx.x * blockDim.x + threadIdx.x;
  if (e >= E) return;
  unsigned long long a = (unsigned long long)offs[e] * (unsigned long long)NW;
  unsigned long long b = (unsigned long long)offs[e + 1] * (unsigned long long)NW;
  int w_lo = (int)((a + T_ - 1) / (unsigned long long)T_);
  int w_hi = (int)((b + T_ - 1) / (unsigned long long)T_);
  for (int w = w_lo; w < w_hi; ++w) wstart[w] = e;
}

// Scatter + fused geometry: writes seik[pos] and g[pos][20] (fp32, float4 x5).
__global__ void scatter_kernel(const int* __restrict__ tbe, int* __restrict__ cursor,
                               const float* __restrict__ edge_vectors,
                               const float* __restrict__ A1, const float* __restrict__ ab1,
                               int* __restrict__ seik, float* __restrict__ gT, int T_) {
  int t = blockIdx.x * blockDim.x + threadIdx.x;
  if (t >= T_) return;
  int2 v = ((const int2*)tbe)[t];
  int pos = atomicAdd(&cursor[v.x], 1);
  seik[pos] = v.y;
  const float* vj = edge_vectors + 3 * (size_t)v.x;
  const float* vk = edge_vectors + 3 * (size_t)v.y;
  float jx = vj[0], jy = vj[1], jz = vj[2];
  float kx = vk[0], ky = vk[1], kz = vk[2];
  float lij = fmaxf(__builtin_amdgcn_sqrtf(jx * jx + jy * jy + jz * jz), 1e-6f);
  float lik = fmaxf(__builtin_amdgcn_sqrtf(kx * kx + ky * ky + kz * kz), 1e-6f);
  float cosv = (jx * kx + jy * ky + jz * kz) * __builtin_amdgcn_rcpf(lij * lik);
  cosv = fminf(fmaxf(cosv, -1.f), 1.f);
  union { float4 v4[5]; float f[NB_]; } gr;
#pragma unroll
  for (int k = 0; k < NB_; ++k)
    gr.f[k] = silu_f(lij * A1[k] + lik * A1[NB_ + k] + cosv * A1[2 * NB_ + k] + ab1[k]);
  float4* gp = (float4*)(gT + (size_t)pos * NB_);
#pragma unroll
  for (int i = 0; i < 5; ++i) gp[i] = gr.v4[i];
}

// ---------------------------------------------------------------------------
// Flat-streamed segmented reduction. Each wave owns segments [es,ee) with a
// balanced triplet count (~T/NW); triplets stream continuously with a deep
// pipeline (Q ring depth 4, eik lookahead 8, G double-buffer, P one segment
// ahead); segment boundaries are uniform-branch flushes.
struct G5 { float4 a, b, c, d, e; };

__device__ __forceinline__ G5 loadG(const char* __restrict__ gc, int t) {
  const float4* p = (const float4*)(
      gc + 80u * (unsigned)__builtin_amdgcn_readfirstlane(t));
  G5 g;
  g.a = p[0]; g.b = p[1]; g.c = p[2]; g.d = p[3]; g.e = p[4];
  return g;
}

__device__ __forceinline__ void body_acc(f32x2& acc, const f32x2 base,
                                         const G5& G, ushort2 qq,
                                         const f32x2* __restrict__ m) {
  const float* Gf = (const float*)&G;
  f32x2 u = base + (f32x2){bf2f(qq.x), bf2f(qq.y)};
  f32x2 ub = fsplat(0.f);
#pragma unroll
  for (int k = 0; k < NB_; k += 2) {
    u  += fsplat(Gf[k])     * m[k];
    ub += fsplat(Gf[k + 1]) * m[k + 1];
  }
  u += ub;
  acc += silu2(u);
}

__global__ __launch_bounds__(256, 6) void seg_kernel(
    const int* __restrict__ offs, const int* __restrict__ seik,
    const float* __restrict__ gT,
    const float* __restrict__ Mfold, const float* __restrict__ b1p,
    const unsigned short* __restrict__ P, const unsigned short* __restrict__ Q,
    const int* __restrict__ wstart,
    float* __restrict__ s_out, int E, int NW) {
  const int lane = threadIdx.x & 63;
  const int w = __builtin_amdgcn_readfirstlane(
      (int)((blockIdx.x * blockDim.x + threadIdx.x) >> 6));
  if (w >= NW) return;

  f32x2 m[NB_];
#pragma unroll
  for (int k = 0; k < NB_; ++k) {
    float2 t2 = *(const float2*)(Mfold + k * D_ + 2 * lane);
    m[k] = (f32x2){t2.x, t2.y};
  }
  const float2 bbt = *(const float2*)(b1p + 2 * lane);
  const f32x2 bb = (f32x2){bbt.x, bbt.y};

  int es = (w == 0) ? 0 : wstart[w];
  int ee = (w == NW - 1) ? E : wstart[w + 1];
  if (es >= ee) return;

  const char* Qc = (const char*)Q;
  const char* Pc = (const char*)P;
  const char* gc = (const char*)gT;
  const unsigned loff = (unsigned)lane * 4u;

  int e = es;
  int t = offs[es];
  const int tend = offs[ee];
  int nxt = offs[es + 1];

  // P pipeline: base for current segment, ppn prefetched for e+1
  ushort2 pp = *(const ushort2*)(Pc + ((unsigned)e << 8) + loff);
  int epn = (e + 1 < E) ? e + 1 : E - 1;
  ushort2 ppn = *(const ushort2*)(Pc + ((unsigned)epn << 8) + loff);
  f32x2 base = (f32x2){bf2f(pp.x), bf2f(pp.y)} + bb;
  f32x2 acc = (f32x2){0.f, 0.f};

  if (t < tend) {
    // Q ring (depth 4) + eik lookahead (t+4..t+7); seik padded to T+8 (pad=0)
    int ek0 = seik[t], ek1 = seik[t + 1], ek2 = seik[t + 2], ek3 = seik[t + 3];
    ushort2 q0 = *(const ushort2*)(Qc + ((unsigned)ek0 << 8) + loff);
    ushort2 q1 = *(const ushort2*)(Qc + ((unsigned)ek1 << 8) + loff);
    ushort2 q2 = *(const ushort2*)(Qc + ((unsigned)ek2 << 8) + loff);
    ushort2 q3 = *(const ushort2*)(Qc + ((unsigned)ek3 << 8) + loff);
    int ekA = seik[t + 4], ekB = seik[t + 5], ekC = seik[t + 6], ekD = seik[t + 7];
    G5 Ga = loadG(gc, t);
    G5 Gb = loadG(gc, t + 1);

    while (t < tend) {
      // ---- even triplet (consumes Ga) ----
      while (t == nxt) {
        *(f32x2*)(s_out + (size_t)e * D_ + 2 * lane) = acc;
        acc = (f32x2){0.f, 0.f};
        ++e;
        nxt = offs[e + 1];
        base = (f32x2){bf2f(ppn.x), bf2f(ppn.y)} + bb;
        int ep = (e + 1 < E) ? e + 1 : E - 1;
        ppn = *(const ushort2*)(Pc + ((unsigned)ep << 8) + loff);
      }
      body_acc(acc, base, Ga, q0, m);
      q0 = q1; q1 = q2; q2 = q3;
      q3 = *(const ushort2*)(Qc + ((unsigned)ekA << 8) + loff);
      ekA = ekB; ekB = ekC; ekC = ekD; ekD = seik[t + 8];
      Ga = loadG(gc, t + 2);
      ++t;
      if (t >= tend) break;
      // ---- odd triplet (consumes Gb) ----
      while (t == nxt) {
        *(f32x2*)(s_out + (size_t)e * D_ + 2 * lane) = acc;
        acc = (f32x2){0.f, 0.f};
        ++e;
        nxt = offs[e + 1];
        base = (f32x2){bf2f(ppn.x), bf2f(ppn.y)} + bb;
        int ep = (e + 1 < E) ? e + 1 : E - 1;
        ppn = *(const ushort2*)(Pc + ((unsigned)ep << 8) + loff);
      }
      body_acc(acc, base, Gb, q0, m);
      q0 = q1; q1 = q2; q2 = q3;
      q3 = *(const ushort2*)(Qc + ((unsigned)ekA << 8) + loff);
      ekA = ekB; ekB = ekC; ekC = ekD; ekD = seik[t + 8];
      Gb = loadG(gc, t + 2);
      ++t;
    }
  }
  // flush current segment and any trailing empty segments in [e, ee)
  while (e < ee) {
    *(f32x2*)(s_out + (size_t)e * D_ + 2 * lane) = acc;
    acc = (f32x2){0.f, 0.f};
    ++e;
  }
}

// ---------------------------------------------------------------------------
// In-place MFMA: out[e] = s[e] @ W2u + cnt[e]*c2 + bu
__global__ __launch_bounds__(256) void out_mfma(float* __restrict__ io,
                                                const unsigned short* __restrict__ W2uT,
                                                const float* __restrict__ c2,
                                                const float* __restrict__ bu,
                                                const int* __restrict__ cnt, int E) {
  const int lane = threadIdx.x & 63;
  const int wave = threadIdx.x >> 6;
  const int e0 = (blockIdx.x * 4 + wave) * 16;
  if (e0 >= E) return;
  const int row = lane & 15;
  const int quad = lane >> 4;
  int e = e0 + row; if (e >= E) e = E - 1;

  union { bf16x8 v; unsigned short u[8]; } afr[4];
  const float* arow = io + (size_t)e * D_ + quad * 8;
#pragma unroll
  for (int kt = 0; kt < 4; ++kt) {
    float4 f0 = *(const float4*)(arow + kt * 32);
    float4 f1 = *(const float4*)(arow + kt * 32 + 4);
    afr[kt].u[0] = f2bf(f0.x); afr[kt].u[1] = f2bf(f0.y);
    afr[kt].u[2] = f2bf(f0.z); afr[kt].u[3] = f2bf(f0.w);
    afr[kt].u[4] = f2bf(f1.x); afr[kt].u[5] = f2bf(f1.y);
    afr[kt].u[6] = f2bf(f1.z); afr[kt].u[7] = f2bf(f1.w);
  }
  float nf[4];
#pragma unroll
  for (int i = 0; i < 4; ++i) {
    int er = e0 + quad * 4 + i;
    nf[i] = (float)cnt[(er < E) ? er : (E - 1)];
  }
#pragma unroll
  for (int nt = 0; nt < 8; ++nt) {
    const unsigned short* wrow = W2uT + ((size_t)(nt * 16 + row)) * 128 + quad * 8;
    f32x4 acc = {0.f, 0.f, 0.f, 0.f};
#pragma unroll
    for (int kt = 0; kt < 4; ++kt) {
      bf16x8 bfr = *(const bf16x8*)(wrow + kt * 32);
      acc = __builtin_amdgcn_mfma_f32_16x16x32_bf16(afr[kt].v, bfr, acc, 0, 0, 0);
    }
    int n = nt * 16 + row;
    float c2n = c2[n], bun = bu[n];
#pragma unroll
    for (int i = 0; i < 4; ++i) {
      int er = e0 + quad * 4 + i;
      if (er < E) io[(size_t)er * D_ + n] = acc[i] + nf[i] * c2n + bun;
    }
  }
}

// ---------------------------------------------------------------------------
extern "C" void kernel_launch(void* const* d_in, const int* in_sizes, int n_in,
                              void* d_out, int out_size, void* d_ws, size_t ws_size,
                              hipStream_t stream) {
  const float* edge_attr    = (const float*)d_in[0];
  const int*   tbe          = (const int*)d_in[2];
  const float* edge_vectors = (const float*)d_in[3];
  const float* A1  = (const float*)d_in[4];
  const float* ab1 = (const float*)d_in[5];
  const float* A2  = (const float*)d_in[6];
  const float* ab2 = (const float*)d_in[7];
  const float* W1  = (const float*)d_in[8];
  const float* b1  = (const float*)d_in[9];
  const float* W2  = (const float*)d_in[10];
  const float* b2  = (const float*)d_in[11];
  const float* Wu  = (const float*)d_in[12];
  const float* bu  = (const float*)d_in[13];
  const int E = in_sizes[0] / D_;
  const int T = in_sizes[2] / 2;
  float* out = (float*)d_out;

  char* w = (char*)d_ws;
  auto carve = [&](size_t bytes) -> char* {
    char* p = w;
    w += (bytes + 255) & ~(size_t)255;
    return p;
  };
  unsigned short* P = (unsigned short*)carve((size_t)E * D_ * 2);
  unsigned short* Q = (unsigned short*)carve((size_t)E * D_ * 2);
  float* gT   = (float*)carve(((size_t)T + 8) * NB_ * 4);   // +8 pad rows (unread values)
  int* seik   = (int*)carve(((size_t)T + 8) * 4);           // +8 pad ints (zeroed)
  int* cnt    = (int*)carve((size_t)E * 4);
  int* pre    = (int*)carve((size_t)E * 4);
  int* offs   = (int*)carve((size_t)(E + 1) * 4);
  int* cursor = (int*)carve((size_t)E * 4);
  int* bsum   = (int*)carve(1024 * 4);
  int* wstart = (int*)carve((size_t)NWAVES * 4);
  float* Mfold = (float*)carve(NB_ * D_ * 4);
  float* b1p   = (float*)carve(D_ * 4);
  unsigned short* W2uT = (unsigned short*)carve(D_ * D_ * 2);
  float* c2    = (float*)carve(D_ * 4);
  unsigned short* W1T = (unsigned short*)carve(256 * 128 * 2);

  const int nb_scan = (E + SCAN_B - 1) / SCAN_B;

  hipMemsetAsync(cnt, 0, (size_t)E * 4, stream);
  hipMemsetAsync(seik + T, 0, 8 * 4, stream);  // zero the index pad

  prep_kernel<<<(51968 + 255) / 256, 256, 0, stream>>>(A2, ab2, W1, b1, W2, Wu, b2,
                                                       Mfold, b1p, W2uT, c2, W1T);
  pq_mfma<<<(E + 63) / 64, 256, 0, stream>>>(edge_attr, W1T, P, Q, E);

  hist_kernel<<<(T + 255) / 256, 256, 0, stream>>>(tbe, cnt, T);
  scan1_kernel<<<nb_scan, SCAN_B, 0, stream>>>(cnt, pre, bsum, E);
  scan2_kernel<<<1, 256, 0, stream>>>(bsum, nb_scan);
  scan3_kernel<<<nb_scan, SCAN_B, 0, stream>>>(pre, bsum, offs, cursor, E, T);
  wfill_kernel<<<(E + 255) / 256, 256, 0, stream>>>(offs, wstart, E, T, NWAVES);
  scatter_kernel<<<(T + 255) / 256, 256, 0, stream>>>(tbe, cursor, edge_vectors,
                                                      A1, ab1, seik, gT, T);

  seg_kernel<<<SEG_BLOCKS, 256, 0, stream>>>(offs, seik, gT, Mfold, b1p, P, Q,
                                             wstart, out, E, NWAVES);
  out_mfma<<<(E + 63) / 64, 256, 0, stream>>>(out, W2uT, c2, bu, cnt, E);
}

// Round 3
// 686.829 us; speedup vs baseline: 1.0947x; 1.0120x over previous
//
#include <hip/hip_runtime.h>
#include <stdint.h>

#define D_ 128
#define NB_ 20
#define SCAN_B 1024
#define SEG_BLOCKS 2048
#define NWAVES (SEG_BLOCKS * 256 / 64)

typedef __bf16 bf16x8 __attribute__((ext_vector_type(8)));
typedef float f32x4 __attribute__((ext_vector_type(4)));
typedef float f32x2 __attribute__((ext_vector_type(2)));

// fast silu: x * rcp(1+exp(-x)); v_rcp_f32 rel-err ~2^-22, fine at bf16 tolerance
__device__ __forceinline__ float silu_f(float x) {
  return x * __builtin_amdgcn_rcpf(1.0f + __expf(-x));
}
__device__ __forceinline__ f32x2 silu2(f32x2 x) {
  return (f32x2){silu_f(x.x), silu_f(x.y)};
}
__device__ __forceinline__ f32x2 fsplat(float x) { return (f32x2){x, x}; }

__device__ __forceinline__ float bf2f(unsigned short u) {
  return __uint_as_float(((unsigned int)u) << 16);
}
__device__ __forceinline__ unsigned short f2bf(float f) {
  unsigned int x = __float_as_uint(f);
  return (unsigned short)((x + 0x7fffu + ((x >> 16) & 1u)) >> 16);
}

// ---------------------------------------------------------------------------
// prep ranges:
//  [0, 2688):           Mfold = A2@W1c (20x128), b1p = b1 + ab2@W1c
//  [2688, 19072):       W2uT bf16: W2uT[n*128+k] = (W2@Wu)[k][n]
//  [19072, 19200):      c2 = b2 @ Wu
//  [19200, 51968):      W1T bf16: W1T[half*128+n][k] = W1[half*128+k][n]
__global__ __launch_bounds__(256) void prep_kernel(
    const float* __restrict__ A2, const float* __restrict__ ab2,
    const float* __restrict__ W1, const float* __restrict__ b1,
    const float* __restrict__ W2, const float* __restrict__ Wu,
    const float* __restrict__ b2,
    float* __restrict__ Mfold, float* __restrict__ b1p,
    unsigned short* __restrict__ W2uT, float* __restrict__ c2,
    unsigned short* __restrict__ W1T) {
  int tid = blockIdx.x * blockDim.x + threadIdx.x;
  if (tid < 21 * D_) {
    int r = tid >> 7, c = tid & (D_ - 1);
    if (r < NB_) {
      float acc = 0.f;
      for (int j = 0; j < NB_; ++j) acc += A2[r * NB_ + j] * W1[(2 * D_ + j) * D_ + c];
      Mfold[r * D_ + c] = acc;
    } else {
      float acc = b1[c];
      for (int j = 0; j < NB_; ++j) acc += ab2[j] * W1[(2 * D_ + j) * D_ + c];
      b1p[c] = acc;
    }
  } else if (tid < 2688 + 16384) {
    int i = tid - 2688;
    int n = i >> 7, k = i & 127;
    float acc = 0.f;
    for (int m = 0; m < D_; ++m) acc += W2[k * D_ + m] * Wu[m * D_ + n];
    W2uT[i] = f2bf(acc);
  } else if (tid < 19072 + 128) {
    int n = tid - 19072;
    float acc = 0.f;
    for (int m = 0; m < D_; ++m) acc += b2[m] * Wu[m * D_ + n];
    c2[n] = acc;
  } else if (tid < 19200 + 32768) {
    int i = tid - 19200;
    int r = i >> 7, k = i & 127;
    int half = r >> 7, n = r & 127;
    W1T[i] = f2bf(W1[(size_t)(half * 128 + k) * D_ + n]);
  }
}

// ---------------------------------------------------------------------------
// MFMA pq: P = edge_attr @ W1[0:128], Q = edge_attr @ W1[128:256], bf16 out.
__global__ __launch_bounds__(256) void pq_mfma(const float* __restrict__ edge_attr,
                                               const unsigned short* __restrict__ W1T,
                                               unsigned short* __restrict__ P,
                                               unsigned short* __restrict__ Q, int E) {
  const int lane = threadIdx.x & 63;
  const int wave = threadIdx.x >> 6;
  const int e0 = (blockIdx.x * 4 + wave) * 16;
  if (e0 >= E) return;
  const int row = lane & 15;
  const int quad = lane >> 4;
  int e = e0 + row; if (e >= E) e = E - 1;

  union { bf16x8 v; unsigned short u[8]; } afr[4];
  const float* arow = edge_attr + (size_t)e * D_ + quad * 8;
#pragma unroll
  for (int kt = 0; kt < 4; ++kt) {
    float4 f0 = *(const float4*)(arow + kt * 32);
    float4 f1 = *(const float4*)(arow + kt * 32 + 4);
    afr[kt].u[0] = f2bf(f0.x); afr[kt].u[1] = f2bf(f0.y);
    afr[kt].u[2] = f2bf(f0.z); afr[kt].u[3] = f2bf(f0.w);
    afr[kt].u[4] = f2bf(f1.x); afr[kt].u[5] = f2bf(f1.y);
    afr[kt].u[6] = f2bf(f1.z); afr[kt].u[7] = f2bf(f1.w);
  }
#pragma unroll
  for (int half = 0; half < 2; ++half) {
    unsigned short* Obase = half ? Q : P;
#pragma unroll
    for (int nt = 0; nt < 8; ++nt) {
      const unsigned short* wrow =
          W1T + ((size_t)(half * 128 + nt * 16 + row)) * 128 + quad * 8;
      f32x4 acc = {0.f, 0.f, 0.f, 0.f};
#pragma unroll
      for (int kt = 0; kt < 4; ++kt) {
        bf16x8 bfr = *(const bf16x8*)(wrow + kt * 32);
        acc = __builtin_amdgcn_mfma_f32_16x16x32_bf16(afr[kt].v, bfr, acc, 0, 0, 0);
      }
      int n = nt * 16 + row;
#pragma unroll
      for (int i = 0; i < 4; ++i) {
        int er = e0 + quad * 4 + i;
        if (er < E) Obase[(size_t)er * D_ + n] = f2bf(acc[i]);
      }
    }
  }
}

// ---------------------------------------------------------------------------
// Counting sort by e_ij
__global__ void hist_kernel(const int* __restrict__ tbe, int* __restrict__ cnt, int T_) {
  int t = blockIdx.x * blockDim.x + threadIdx.x;
  if (t < T_) atomicAdd(&cnt[((const int2*)tbe)[t].x], 1);
}

__global__ __launch_bounds__(SCAN_B) void scan1_kernel(const int* __restrict__ cnt,
                                                       int* __restrict__ pre,
                                                       int* __restrict__ bsum, int E) {
  __shared__ int lds[SCAN_B];
  int tid = threadIdx.x, i = blockIdx.x * SCAN_B + tid;
  int v = (i < E) ? cnt[i] : 0;
  lds[tid] = v;
  __syncthreads();
  for (int d = 1; d < SCAN_B; d <<= 1) {
    int add = (tid >= d) ? lds[tid - d] : 0;
    __syncthreads();
    lds[tid] += add;
    __syncthreads();
  }
  if (i < E) pre[i] = lds[tid] - v;
  if (tid == SCAN_B - 1) bsum[blockIdx.x] = lds[tid];
}

__global__ void scan2_kernel(int* __restrict__ bsum, int nb) {
  __shared__ int lds[256];
  int tid = threadIdx.x;
  int v = (tid < nb) ? bsum[tid] : 0;
  lds[tid] = v;
  __syncthreads();
  for (int d = 1; d < 256; d <<= 1) {
    int add = (tid >= d) ? lds[tid - d] : 0;
    __syncthreads();
    lds[tid] += add;
    __syncthreads();
  }
  if (tid < nb) bsum[tid] = lds[tid] - v;
}

__global__ __launch_bounds__(SCAN_B) void scan3_kernel(const int* __restrict__ pre,
                                                       const int* __restrict__ bsum,
                                                       int* __restrict__ offs,
                                                       int* __restrict__ cursor, int E, int T_) {
  int i = blockIdx.x * SCAN_B + threadIdx.x;
  if (i < E) {
    int o = pre[i] + bsum[blockIdx.x];
    offs[i] = o;
    cursor[i] = o;
  }
  if (i == 0) offs[E] = T_;
}

// Per-wave balanced segment ranges: wstart[w] = e such that triplet target
// w*T/NW lands in segment e.
__global__ __launch_bounds__(256) void wfill_kernel(const int* __restrict__ offs,
                                                    int* __restrict__ wstart,
                                                    int E, int T_, int NW) {
  int e = blockIdx.x * blockDim.x + threadIdx.x;
  if (e >= E) return;
  unsigned long long a = (unsigned long long)offs[e] * (unsigned long long)NW;
  unsigned long long b = (unsigned long long)offs[e + 1] * (unsigned long long)NW;
  int w_lo = (int)((a + T_ - 1) / (unsigned long long)T_);
  int w_hi = (int)((b + T_ - 1) / (unsigned long long)T_);
  for (int w = w_lo; w < w_hi; ++w) wstart[w] = e;
}

// Light scatter: only the 8B index pair goes to the random position.
__global__ void scatter_kernel(const int* __restrict__ tbe, int* __restrict__ cursor,
                               int2* __restrict__ seik2, int T_) {
  int t = blockIdx.x * blockDim.x + threadIdx.x;
  if (t >= T_) return;
  int2 v = ((const int2*)tbe)[t];
  int pos = atomicAdd(&cursor[v.x], 1);
  seik2[pos] = make_int2(v.y, v.x);  // {e_ik, e_ij}
}

// Geometry pass in sorted order: fully coalesced 80B gT rows.
__global__ __launch_bounds__(256) void geom_kernel(const int2* __restrict__ seik2,
                                                   const float* __restrict__ edge_vectors,
                                                   const float* __restrict__ A1,
                                                   const float* __restrict__ ab1,
                                                   float* __restrict__ gT, int T_) {
  int t = blockIdx.x * blockDim.x + threadIdx.x;
  if (t >= T_) return;
  int2 s = seik2[t];
  const float* vj = edge_vectors + 3 * (size_t)s.y;
  const float* vk = edge_vectors + 3 * (size_t)s.x;
  float jx = vj[0], jy = vj[1], jz = vj[2];
  float kx = vk[0], ky = vk[1], kz = vk[2];
  float lij = fmaxf(__builtin_amdgcn_sqrtf(jx * jx + jy * jy + jz * jz), 1e-6f);
  float lik = fmaxf(__builtin_amdgcn_sqrtf(kx * kx + ky * ky + kz * kz), 1e-6f);
  float cosv = (jx * kx + jy * ky + jz * kz) * __builtin_amdgcn_rcpf(lij * lik);
  cosv = fminf(fmaxf(cosv, -1.f), 1.f);
  union { float4 v4[5]; float f[NB_]; } gr;
#pragma unroll
  for (int k = 0; k < NB_; ++k)
    gr.f[k] = silu_f(lij * A1[k] + lik * A1[NB_ + k] + cosv * A1[2 * NB_ + k] + ab1[k]);
  float4* gp = (float4*)(gT + (size_t)t * NB_);
#pragma unroll
  for (int i = 0; i < 5; ++i) gp[i] = gr.v4[i];
}

// ---------------------------------------------------------------------------
// Flat-streamed segmented reduction (unchanged structure). Output rows are
// written as bf16 packed into the FRONT 256B of each 512B d_out row slot:
// bit-identical to the f2bf out_mfma performed anyway, halves s traffic.
struct G5 { float4 a, b, c, d, e; };

__device__ __forceinline__ G5 loadG(const char* __restrict__ gc, int t) {
  const float4* p = (const float4*)(
      gc + 80u * (unsigned)__builtin_amdgcn_readfirstlane(t));
  G5 g;
  g.a = p[0]; g.b = p[1]; g.c = p[2]; g.d = p[3]; g.e = p[4];
  return g;
}

__device__ __forceinline__ void body_acc(f32x2& acc, const f32x2 base,
                                         const G5& G, ushort2 qq,
                                         const f32x2* __restrict__ m) {
  const float* Gf = (const float*)&G;
  f32x2 u = base + (f32x2){bf2f(qq.x), bf2f(qq.y)};
  f32x2 ub = fsplat(0.f);
#pragma unroll
  for (int k = 0; k < NB_; k += 2) {
    u  += fsplat(Gf[k])     * m[k];
    ub += fsplat(Gf[k + 1]) * m[k + 1];
  }
  u += ub;
  acc += silu2(u);
}

__global__ __launch_bounds__(256, 6) void seg_kernel(
    const int* __restrict__ offs, const int2* __restrict__ seik2,
    const float* __restrict__ gT,
    const float* __restrict__ Mfold, const float* __restrict__ b1p,
    const unsigned short* __restrict__ P, const unsigned short* __restrict__ Q,
    const int* __restrict__ wstart,
    char* __restrict__ s_out, int E, int NW) {
  const int lane = threadIdx.x & 63;
  const int w = __builtin_amdgcn_readfirstlane(
      (int)((blockIdx.x * blockDim.x + threadIdx.x) >> 6));
  if (w >= NW) return;

  f32x2 m[NB_];
#pragma unroll
  for (int k = 0; k < NB_; ++k) {
    float2 t2 = *(const float2*)(Mfold + k * D_ + 2 * lane);
    m[k] = (f32x2){t2.x, t2.y};
  }
  const float2 bbt = *(const float2*)(b1p + 2 * lane);
  const f32x2 bb = (f32x2){bbt.x, bbt.y};

  int es = (w == 0) ? 0 : wstart[w];
  int ee = (w == NW - 1) ? E : wstart[w + 1];
  if (es >= ee) return;

  const char* Qc = (const char*)Q;
  const char* Pc = (const char*)P;
  const char* gc = (const char*)gT;
  const unsigned loff = (unsigned)lane * 4u;

  int e = es;
  int t = offs[es];
  const int tend = offs[ee];
  int nxt = offs[es + 1];

  ushort2 pp = *(const ushort2*)(Pc + ((unsigned)e << 8) + loff);
  int epn = (e + 1 < E) ? e + 1 : E - 1;
  ushort2 ppn = *(const ushort2*)(Pc + ((unsigned)epn << 8) + loff);
  f32x2 base = (f32x2){bf2f(pp.x), bf2f(pp.y)} + bb;
  f32x2 acc = (f32x2){0.f, 0.f};

  if (t < tend) {
    // Q ring (depth 4) + eik lookahead; seik2 padded to T+8 (pad=0)
    int ek0 = seik2[t].x, ek1 = seik2[t + 1].x, ek2 = seik2[t + 2].x, ek3 = seik2[t + 3].x;
    ushort2 q0 = *(const ushort2*)(Qc + ((unsigned)ek0 << 8) + loff);
    ushort2 q1 = *(const ushort2*)(Qc + ((unsigned)ek1 << 8) + loff);
    ushort2 q2 = *(const ushort2*)(Qc + ((unsigned)ek2 << 8) + loff);
    ushort2 q3 = *(const ushort2*)(Qc + ((unsigned)ek3 << 8) + loff);
    int ekA = seik2[t + 4].x, ekB = seik2[t + 5].x, ekC = seik2[t + 6].x, ekD = seik2[t + 7].x;
    G5 Ga = loadG(gc, t);
    G5 Gb = loadG(gc, t + 1);

    while (t < tend) {
      // ---- even triplet (consumes Ga) ----
      while (t == nxt) {
        *(ushort2*)(s_out + ((size_t)e << 9) + loff) =
            make_ushort2(f2bf(acc.x), f2bf(acc.y));
        acc = (f32x2){0.f, 0.f};
        ++e;
        nxt = offs[e + 1];
        base = (f32x2){bf2f(ppn.x), bf2f(ppn.y)} + bb;
        int ep = (e + 1 < E) ? e + 1 : E - 1;
        ppn = *(const ushort2*)(Pc + ((unsigned)ep << 8) + loff);
      }
      body_acc(acc, base, Ga, q0, m);
      q0 = q1; q1 = q2; q2 = q3;
      q3 = *(const ushort2*)(Qc + ((unsigned)ekA << 8) + loff);
      ekA = ekB; ekB = ekC; ekC = ekD;
      ekD = seik2[__builtin_amdgcn_readfirstlane(t + 8)].x;
      Ga = loadG(gc, t + 2);
      ++t;
      if (t >= tend) break;
      // ---- odd triplet (consumes Gb) ----
      while (t == nxt) {
        *(ushort2*)(s_out + ((size_t)e << 9) + loff) =
            make_ushort2(f2bf(acc.x), f2bf(acc.y));
        acc = (f32x2){0.f, 0.f};
        ++e;
        nxt = offs[e + 1];
        base = (f32x2){bf2f(ppn.x), bf2f(ppn.y)} + bb;
        int ep = (e + 1 < E) ? e + 1 : E - 1;
        ppn = *(const ushort2*)(Pc + ((unsigned)ep << 8) + loff);
      }
      body_acc(acc, base, Gb, q0, m);
      q0 = q1; q1 = q2; q2 = q3;
      q3 = *(const ushort2*)(Qc + ((unsigned)ekA << 8) + loff);
      ekA = ekB; ekB = ekC; ekC = ekD;
      ekD = seik2[__builtin_amdgcn_readfirstlane(t + 8)].x;
      Gb = loadG(gc, t + 2);
      ++t;
    }
  }
  // flush current segment and any trailing empty segments in [e, ee)
  while (e < ee) {
    *(ushort2*)(s_out + ((size_t)e << 9) + loff) =
        make_ushort2(f2bf(acc.x), f2bf(acc.y));
    acc = (f32x2){0.f, 0.f};
    ++e;
  }
}

// ---------------------------------------------------------------------------
// In-place MFMA: out[e] = s_bf16[e] @ W2u + cnt[e]*c2 + bu.
// s is bf16 in the front 256B of each 512B row slot of io; each wave reads
// its own 16 rows fully before writing them (same in-place discipline as
// the fp32 version; E is a multiple of 16 so no row clamping occurs).
__global__ __launch_bounds__(256) void out_mfma(float* __restrict__ io,
                                                const unsigned short* __restrict__ W2uT,
                                                const float* __restrict__ c2,
                                                const float* __restrict__ bu,
                                                const int* __restrict__ cnt, int E) {
  const int lane = threadIdx.x & 63;
  const int wave = threadIdx.x >> 6;
  const int e0 = (blockIdx.x * 4 + wave) * 16;
  if (e0 >= E) return;
  const int row = lane & 15;
  const int quad = lane >> 4;
  int e = e0 + row; if (e >= E) e = E - 1;

  bf16x8 afr[4];
  const char* arow = (const char*)io + ((size_t)e << 9) + quad * 16;
#pragma unroll
  for (int kt = 0; kt < 4; ++kt)
    afr[kt] = *(const bf16x8*)(arow + kt * 64);

  float nf[4];
#pragma unroll
  for (int i = 0; i < 4; ++i) {
    int er = e0 + quad * 4 + i;
    nf[i] = (float)cnt[(er < E) ? er : (E - 1)];
  }
#pragma unroll
  for (int nt = 0; nt < 8; ++nt) {
    const unsigned short* wrow = W2uT + ((size_t)(nt * 16 + row)) * 128 + quad * 8;
    f32x4 acc = {0.f, 0.f, 0.f, 0.f};
#pragma unroll
    for (int kt = 0; kt < 4; ++kt) {
      bf16x8 bfr = *(const bf16x8*)(wrow + kt * 32);
      acc = __builtin_amdgcn_mfma_f32_16x16x32_bf16(afr[kt], bfr, acc, 0, 0, 0);
    }
    int n = nt * 16 + row;
    float c2n = c2[n], bun = bu[n];
#pragma unroll
    for (int i = 0; i < 4; ++i) {
      int er = e0 + quad * 4 + i;
      if (er < E) io[(size_t)er * D_ + n] = acc[i] + nf[i] * c2n + bun;
    }
  }
}

// ---------------------------------------------------------------------------
extern "C" void kernel_launch(void* const* d_in, const int* in_sizes, int n_in,
                              void* d_out, int out_size, void* d_ws, size_t ws_size,
                              hipStream_t stream) {
  const float* edge_attr    = (const float*)d_in[0];
  const int*   tbe          = (const int*)d_in[2];
  const float* edge_vectors = (const float*)d_in[3];
  const float* A1  = (const float*)d_in[4];
  const float* ab1 = (const float*)d_in[5];
  const float* A2  = (const float*)d_in[6];
  const float* ab2 = (const float*)d_in[7];
  const float* W1  = (const float*)d_in[8];
  const float* b1  = (const float*)d_in[9];
  const float* W2  = (const float*)d_in[10];
  const float* b2  = (const float*)d_in[11];
  const float* Wu  = (const float*)d_in[12];
  const float* bu  = (const float*)d_in[13];
  const int E = in_sizes[0] / D_;
  const int T = in_sizes[2] / 2;
  float* out = (float*)d_out;

  char* w = (char*)d_ws;
  auto carve = [&](size_t bytes) -> char* {
    char* p = w;
    w += (bytes + 255) & ~(size_t)255;
    return p;
  };
  unsigned short* P = (unsigned short*)carve((size_t)E * D_ * 2);
  unsigned short* Q = (unsigned short*)carve((size_t)E * D_ * 2);
  float* gT   = (float*)carve(((size_t)T + 8) * NB_ * 4);   // +8 pad rows (unread values)
  int2* seik2 = (int2*)carve(((size_t)T + 8) * 8);          // +8 pad pairs (zeroed)
  int* cnt    = (int*)carve((size_t)E * 4);
  int* pre    = (int*)carve((size_t)E * 4);
  int* offs   = (int*)carve((size_t)(E + 1) * 4);
  int* cursor = (int*)carve((size_t)E * 4);
  int* bsum   = (int*)carve(1024 * 4);
  int* wstart = (int*)carve((size_t)NWAVES * 4);
  float* Mfold = (float*)carve(NB_ * D_ * 4);
  float* b1p   = (float*)carve(D_ * 4);
  unsigned short* W2uT = (unsigned short*)carve(D_ * D_ * 2);
  float* c2    = (float*)carve(D_ * 4);
  unsigned short* W1T = (unsigned short*)carve(256 * 128 * 2);

  const int nb_scan = (E + SCAN_B - 1) / SCAN_B;

  hipMemsetAsync(cnt, 0, (size_t)E * 4, stream);
  hipMemsetAsync(seik2 + T, 0, 8 * 8, stream);  // zero the index pad

  prep_kernel<<<(51968 + 255) / 256, 256, 0, stream>>>(A2, ab2, W1, b1, W2, Wu, b2,
                                                       Mfold, b1p, W2uT, c2, W1T);
  pq_mfma<<<(E + 63) / 64, 256, 0, stream>>>(edge_attr, W1T, P, Q, E);

  hist_kernel<<<(T + 255) / 256, 256, 0, stream>>>(tbe, cnt, T);
  scan1_kernel<<<nb_scan, SCAN_B, 0, stream>>>(cnt, pre, bsum, E);
  scan2_kernel<<<1, 256, 0, stream>>>(bsum, nb_scan);
  scan3_kernel<<<nb_scan, SCAN_B, 0, stream>>>(pre, bsum, offs, cursor, E, T);
  wfill_kernel<<<(E + 255) / 256, 256, 0, stream>>>(offs, wstart, E, T, NWAVES);
  scatter_kernel<<<(T + 255) / 256, 256, 0, stream>>>(tbe, cursor, seik2, T);
  geom_kernel<<<(T + 255) / 256, 256, 0, stream>>>(seik2, edge_vectors, A1, ab1, gT, T);

  seg_kernel<<<SEG_BLOCKS, 256, 0, stream>>>(offs, seik2, gT, Mfold, b1p, P, Q,
                                             wstart, (char*)out, E, NWAVES);
  out_mfma<<<(E + 63) / 64, 256, 0, stream>>>(out, W2uT, c2, bu, cnt, E);
}